// Round 12
// baseline (461.925 us; speedup 1.0000x reference)
//
#include <hip/hip_runtime.h>

#define D_ 1024
#define S_ 2048
#define B_ 32
#define BM 256
#define BN 256
#define BK 64
#define NKT 32  // K tiles: 16 from W/k + 16 from U/q (BK=64)

typedef __attribute__((ext_vector_type(8))) _Float16 f16x8;  // 4 VGPR MFMA operand
typedef __attribute__((ext_vector_type(16))) float f32x16;   // MFMA 32x32 acc

// async global->LDS, 16B per lane; LDS dest = wave-uniform base + lane*16.
__device__ __forceinline__ void async_ld16(const void* g, void* l) {
  __builtin_amdgcn_global_load_lds(
      (const __attribute__((address_space(1))) void*)g,
      (__attribute__((address_space(3))) void*)l, 16, 0, 0);
}

// ---------------------------------------------------------------------------
// prep: W,U -> f16, FRAGMENT ORDER per 256x64 A-tile (2048 granules of 8):
//   granule = ((ks*8 + wr*4 + fm) << 6) | lane   (verified R9-R11)
// ---------------------------------------------------------------------------
__global__ void prep_kernel(const float* __restrict__ W, const float* __restrict__ U,
                            _Float16* __restrict__ wf, _Float16* __restrict__ uf) {
  int t = blockIdx.x * blockDim.x + threadIdx.x;  // [0, 131072) granules
  const float* src = blockIdx.y ? U : W;
  _Float16* dst = blockIdx.y ? uf : wf;

  int tile = t >> 11;        // [0,64) = dblk*16 + ktt
  int g    = t & 2047;
  int top  = g >> 6;         // [0,32) = ks*8 + wr*4 + fm
  int ks = top >> 3, wr = (top >> 2) & 1, fm = top & 3;
  int lane = g & 63, l31 = lane & 31, lhi = lane >> 5;
  int row   = wr * 128 + fm * 32 + l31;
  int chunk = ks * 2 + lhi;
  int d = (tile >> 4) * 256 + row;
  int e = (tile & 15) * 64 + chunk * 8;

  const float* p = src + (size_t)d * D_ + e;
  f16x8 hv;
#pragma unroll
  for (int j = 0; j < 8; ++j) hv[j] = (_Float16)p[j];  // RN
  *(f16x8*)(dst + (size_t)t * 8) = hv;                 // linear, coalesced
}

// ---------------------------------------------------------------------------
// kqprep: k,q (f32 [b,e,s]) -> f16 fragment-order B-tiles in ws (R11 verified).
// ---------------------------------------------------------------------------
__global__ void kqprep_kernel(const float* __restrict__ kten, const float* __restrict__ qten,
                              _Float16* __restrict__ bfmt) {
  size_t t = (size_t)blockIdx.x * 256 + threadIdx.x;  // [0, 16777216)
  int g    = (int)(t & 2047);
  int tile = (int)(t >> 11);
  int st   = tile & 7;
  int ktt  = (tile >> 3) & 15;
  int half = (tile >> 7) & 1;
  int b    = tile >> 8;
  int l31 = g & 31, clh = (g >> 5) & 1, w2 = (g >> 6) & 7, cks = g >> 9;
  int n = w2 * 32 + l31;
  int c = cks * 2 + clh;
  int e = ktt * 64 + c * 8;
  int s = st * 256 + n;

  const float* src = (half ? qten : kten) + (size_t)b * (D_ * S_) + (size_t)e * S_ + s;
  f16x8 hv;
#pragma unroll
  for (int j = 0; j < 8; ++j) hv[j] = (_Float16)src[(size_t)j * S_];  // RN
  *(f16x8*)(bfmt + t * 8) = hv;
}

// ---------------------------------------------------------------------------
// gemm v12: R11 pure-gll geometry + m201-style fine phase schedule.
// Per kt, 4 phases; each: {6 ds_read | 2 gll | s_barrier | setprio 8 MFMA
// setprio | [vmcnt] | s_barrier | sched_barrier(0)}.
// Quarter ledger (per wave, 2 gll instr per quarter, issue order A0,B0,A1,B1):
//   vmcnt(4) at end of ph1: retires A1,B1(kt)  (needed by ph2 reads)
//   vmcnt(4) at end of ph3: retires A0,B0(kt+1) (needed by next kt ph0)
// Never drains to 0 mid-loop; each gll batch gets a full K-tile of cover.
// ---------------------------------------------------------------------------
__global__ void __launch_bounds__(512, 2)
gemm_kernel(const float* __restrict__ v,
            const _Float16* __restrict__ wf, const _Float16* __restrict__ uf,
            const _Float16* __restrict__ bfmt,
            float* __restrict__ partials) {
  __shared__ __align__(16) _Float16 Af[2][BM * BK];  // 2 x 32 KB
  __shared__ __align__(16) _Float16 Bf[2][BN * BK];  // 2 x 32 KB
  __shared__ float vbuf[BM];
  __shared__ float red[2][BN];

  const int tid  = threadIdx.x;
  const int lane = tid & 63;
  const int wid  = tid >> 6;
  const int wr   = wid >> 2;        // [0,2) d-half (128 rows)
  const int wc   = wid & 3;         // [0,4) s-quarter (64 cols)

  int bid  = blockIdx.x;
  int g    = ((bid >> 5) << 3) | (bid & 7);  // [0,256): 4 dblk siblings same XCD
  int dblk = (bid >> 3) & 3;
  int st   = g & 7;
  int b    = g >> 3;
  int s0   = st * BN;

  if (tid < BM) vbuf[tid] = v[(size_t)b * D_ + dblk * BM + tid];

  f32x16 acc[4][2];
#pragma unroll
  for (int i = 0; i < 4; ++i)
#pragma unroll
    for (int j = 0; j < 2; ++j)
#pragma unroll
      for (int r = 0; r < 16; ++r) acc[i][j][r] = 0.0f;

#define PH_FENCE asm volatile("" ::: "memory")

// A half-tile: part 0 = granules [0,1024) (ks 0,1), part 1 = [1024,2048).
#define GLLA2(ktn, buf, part) do {                                             \
    const int half_ = (ktn) >> 4, ktt_ = (ktn) & 15;                           \
    const _Float16* at_ = (half_ ? uf : wf) + (size_t)(dblk * 16 + ktt_) * 16384; \
    async_ld16(at_ + (size_t)(tid + (part) * 1024) * 8,                        \
               &Af[buf][(size_t)(tid + (part) * 1024) * 8]);                   \
    async_ld16(at_ + (size_t)(tid + (part) * 1024 + 512) * 8,                  \
               &Af[buf][(size_t)(tid + (part) * 1024 + 512) * 8]);             \
  } while (0)

// B half-tile from prepped fragment-order tiles (part 0 = ks 0,1).
#define GLLB2(ktn, buf, part) do {                                             \
    const int half_ = (ktn) >> 4, ktt_ = (ktn) & 15;                           \
    const _Float16* bt_ = bfmt + ((size_t)(((b * 2 + half_) * 16 + ktt_) * 8 + st)) * 16384; \
    async_ld16(bt_ + (size_t)(tid + (part) * 1024) * 8,                        \
               &Bf[buf][(size_t)(tid + (part) * 1024) * 8]);                   \
    async_ld16(bt_ + (size_t)(tid + (part) * 1024 + 512) * 8,                  \
               &Bf[buf][(size_t)(tid + (part) * 1024 + 512) * 8]);             \
  } while (0)

#define WAIT4 asm volatile("s_waitcnt vmcnt(4)" ::: "memory")
#define WAIT0 asm volatile("s_waitcnt vmcnt(0)" ::: "memory")

// One phase: ds_read 6 frags | issue | BAR | 8 MFMA (prio) | wait | BAR | SB
#define PHASE(cur_, ks_, ISSUE, WAITC) do {                                    \
    PH_FENCE;                                                                  \
    f16x8 af_[4], bf_[2];                                                      \
    _Pragma("unroll")                                                          \
    for (int fm = 0; fm < 4; ++fm)                                             \
      af_[fm] = *(const f16x8*)&Af[cur_][(size_t)(((ks_) * 8 + wr * 4 + fm) * 64 + lane) * 8]; \
    _Pragma("unroll")                                                          \
    for (int fn = 0; fn < 2; ++fn)                                             \
      bf_[fn] = *(const f16x8*)&Bf[cur_][(size_t)(((ks_) * 8 + wc * 2 + fn) * 64 + lane) * 8]; \
    ISSUE;                                                                     \
    __builtin_amdgcn_s_barrier();                                              \
    __builtin_amdgcn_s_setprio(1);                                             \
    _Pragma("unroll")                                                          \
    for (int fm = 0; fm < 4; ++fm)                                             \
      _Pragma("unroll")                                                        \
      for (int fn = 0; fn < 2; ++fn)                                           \
        acc[fm][fn] = __builtin_amdgcn_mfma_f32_32x32x16_f16(af_[fm], bf_[fn], acc[fm][fn], 0, 0, 0); \
    __builtin_amdgcn_s_setprio(0);                                             \
    WAITC;                                                                     \
    __builtin_amdgcn_s_barrier();                                              \
    __builtin_amdgcn_sched_barrier(0);                                         \
  } while (0)

  // --- prologue: issue all 4 quarters of kt=0 (order A0,B0,A1,B1);
  //     retire A0,B0 (vmcnt(4)), leave A1,B1 in flight ---------------------
  PH_FENCE;
  GLLA2(0, 0, 0); GLLB2(0, 0, 0);
  GLLA2(0, 0, 1); GLLB2(0, 0, 1);
  WAIT4;
  __builtin_amdgcn_s_barrier();
  __builtin_amdgcn_sched_barrier(0);

  // --- main loop kt = 0..30 (uniform; issues for kt+1 <= 31) ----------------
  for (int kt = 0; kt < NKT - 1; ++kt) {
    const int cur = kt & 1, nxt = cur ^ 1;
    PHASE(cur, 0, GLLA2(kt + 1, nxt, 0), );
    PHASE(cur, 1, GLLB2(kt + 1, nxt, 0), WAIT4);  // retires A1,B1(kt)
    PHASE(cur, 2, GLLA2(kt + 1, nxt, 1), );
    PHASE(cur, 3, GLLB2(kt + 1, nxt, 1), WAIT4);  // retires A0,B0(kt+1)
  }
  // --- kt = 31 (cur = 1): no more issues; drain remaining 4 at mid-kt -------
  PHASE(1, 0, , );
  PHASE(1, 1, , WAIT0);  // retires A1,B1(31) before ph2 reads
  PHASE(1, 2, , );
  PHASE(1, 3, , );

#undef PHASE
#undef WAIT0
#undef WAIT4
#undef GLLB2
#undef GLLA2
#undef PH_FENCE

  // ---- epilogue: tanh, weight by v[d], column-reduce the 256 d-rows ----
  float psum[2] = {0.f, 0.f};
#pragma unroll
  for (int fm = 0; fm < 4; ++fm)
#pragma unroll
    for (int fn = 0; fn < 2; ++fn)
#pragma unroll
      for (int r = 0; r < 16; ++r) {
        // C/D layout: col = lane&31, row = (r&3)+8*(r>>2)+4*(lane>>5)
        int row = wr * 128 + fm * 32 + (r & 3) + 8 * (r >> 2) + 4 * (lane >> 5);
        float x  = acc[fm][fn][r];
        float th = 1.0f - 2.0f / (__expf(2.0f * x) + 1.0f);  // tanh(x)
        psum[fn] += vbuf[row] * th;
      }
#pragma unroll
  for (int fn = 0; fn < 2; ++fn) psum[fn] += __shfl_xor(psum[fn], 32);
  if (lane < 32) {
    red[wr][wc * 64 + lane]      = psum[0];
    red[wr][wc * 64 + 32 + lane] = psum[1];
  }
  __syncthreads();
  if (tid < BN) {
    float val = red[0][tid] + red[1][tid];
    partials[(size_t)(dblk * B_ + b) * S_ + s0 + tid] = val;
  }
}

// ---------------------------------------------------------------------------
// gemm fallback = R10 verbatim (reg-staged B, counted vmcnt(32)); used when
// ws_size can't hold the 256MB prepped-B buffer.
// ---------------------------------------------------------------------------
__global__ void __launch_bounds__(512, 2)
gemm_fb_kernel(const float* __restrict__ kten, const float* __restrict__ qten,
               const float* __restrict__ v,
               const _Float16* __restrict__ wf, const _Float16* __restrict__ uf,
               float* __restrict__ partials) {
  __shared__ __align__(16) _Float16 Af[2][BM * BK];
  __shared__ __align__(16) _Float16 Bf[2][BN * BK];
  __shared__ float vbuf[BM];
  __shared__ float red[2][BN];

  const int tid  = threadIdx.x;
  const int lane = tid & 63;
  const int wid  = tid >> 6;
  const int wr   = wid >> 2;
  const int wc   = wid & 3;

  int bid  = blockIdx.x;
  int g    = ((bid >> 5) << 3) | (bid & 7);
  int dblk = (bid >> 3) & 3;
  int st   = g & 7;
  int b    = g >> 3;
  int s0   = st * BN;

  if (tid < BM) vbuf[tid] = v[(size_t)b * D_ + dblk * BM + tid];

  f32x16 acc[4][2];
#pragma unroll
  for (int i = 0; i < 4; ++i)
#pragma unroll
    for (int j = 0; j < 2; ++j)
#pragma unroll
      for (int r = 0; r < 16; ++r) acc[i][j][r] = 0.0f;

  const int nB = tid & 255;
  const int kq = tid >> 8;

#define PH_FENCE_F asm volatile("" ::: "memory")
#define PH_BAR_F __builtin_amdgcn_s_barrier()

#define GLLA_F(ktn, buf, part) do {                                            \
    const int half_ = (ktn) >> 4, ktt_ = (ktn) & 15;                           \
    const _Float16* at_ = (half_ ? uf : wf) + (size_t)(dblk * 16 + ktt_) * 16384; \
    async_ld16(at_ + (size_t)(tid + (part) * 1024) * 8,                        \
               &Af[buf][(size_t)(tid + (part) * 1024) * 8]);                   \
    async_ld16(at_ + (size_t)(tid + (part) * 1024 + 512) * 8,                  \
               &Af[buf][(size_t)(tid + (part) * 1024 + 512) * 8]);             \
  } while (0)

#define LOADB_F(ktn, xv, h) do {                                               \
    const int half_ = (ktn) >> 4, ktt_ = (ktn) & 15;                           \
    const float* col_ = (half_ ? qten : kten) + (size_t)b * (D_ * S_)          \
                        + (size_t)(ktt_ * 64) * S_ + s0 + nB                   \
                        + (size_t)(kq * 32) * S_;                              \
    _Pragma("unroll")                                                          \
    for (int j = 16 * (h); j < 16 * (h) + 16; ++j) xv[j] = col_[(size_t)j * S_]; \
  } while (0)

#define CVTWRITE_F(xv, buf) do {                                               \
    _Pragma("unroll")                                                          \
    for (int cl = 0; cl < 4; ++cl) {                                           \
      f16x8 hv_;                                                               \
      _Pragma("unroll")                                                        \
      for (int w = 0; w < 8; ++w) hv_[w] = (_Float16)xv[cl * 8 + w];           \
      int c_ = kq * 4 + cl, cks_ = c_ >> 1, clh_ = c_ & 1;                     \
      int gnl_ = ((cks_ * 8 + (nB >> 6) * 2 + ((nB >> 5) & 1)) << 6)           \
                 | (clh_ << 5) | (nB & 31);                                    \
      *(f16x8*)&Bf[buf][(size_t)gnl_ * 8] = hv_;                               \
    }                                                                          \
  } while (0)

#define COMPUTE_PHASE_F(cur_, ks_) do {                                        \
    f16x8 af_[4], bf_[2];                                                      \
    _Pragma("unroll")                                                          \
    for (int fm = 0; fm < 4; ++fm)                                             \
      af_[fm] = *(const f16x8*)&Af[cur_][(size_t)(((ks_) * 8 + wr * 4 + fm) * 64 + lane) * 8]; \
    _Pragma("unroll")                                                          \
    for (int fn = 0; fn < 2; ++fn)                                             \
      bf_[fn] = *(const f16x8*)&Bf[cur_][(size_t)(((ks_) * 8 + wc * 2 + fn) * 64 + lane) * 8]; \
    __builtin_amdgcn_s_setprio(1);                                             \
    _Pragma("unroll")                                                          \
    for (int fm = 0; fm < 4; ++fm)                                             \
      _Pragma("unroll")                                                        \
      for (int fn = 0; fn < 2; ++fn)                                           \
        acc[fm][fn] = __builtin_amdgcn_mfma_f32_32x32x16_f16(af_[fm], bf_[fn], acc[fm][fn], 0, 0, 0); \
    __builtin_amdgcn_s_setprio(0);                                             \
  } while (0)

#define STEP_F(kt_, cur_, xvC_, xvN_) do {                                     \
    const int nxt_ = (cur_) ^ 1;                                               \
    PH_FENCE_F; GLLA_F((kt_) + 1, nxt_, 0); COMPUTE_PHASE_F(cur_, 0); PH_BAR_F;\
    PH_FENCE_F; GLLA_F((kt_) + 1, nxt_, 1); COMPUTE_PHASE_F(cur_, 1); PH_BAR_F;\
    PH_FENCE_F; LOADB_F((kt_) + 2, xvN_, 0); COMPUTE_PHASE_F(cur_, 2); PH_BAR_F;\
    PH_FENCE_F; LOADB_F((kt_) + 2, xvN_, 1); CVTWRITE_F(xvC_, nxt_);           \
              COMPUTE_PHASE_F(cur_, 3);                                        \
    asm volatile("s_waitcnt vmcnt(32) lgkmcnt(0)" ::: "memory");               \
    PH_BAR_F;                                                                  \
    __builtin_amdgcn_sched_barrier(0);                                         \
  } while (0)

  float xvA[32], xvB[32];
  LOADB_F(0, xvA, 0); LOADB_F(0, xvA, 1);
  GLLA_F(0, 0, 0);    GLLA_F(0, 0, 1);
  LOADB_F(1, xvB, 0); LOADB_F(1, xvB, 1);
  CVTWRITE_F(xvA, 0);
  __syncthreads();

  for (int it = 0; it < 15; ++it) {
    STEP_F(2 * it,     0, xvB, xvA);
    STEP_F(2 * it + 1, 1, xvA, xvB);
  }

  PH_FENCE_F; GLLA_F(31, 1, 0); COMPUTE_PHASE_F(0, 0); PH_BAR_F;
  PH_FENCE_F; GLLA_F(31, 1, 1); COMPUTE_PHASE_F(0, 1); PH_BAR_F;
  PH_FENCE_F; COMPUTE_PHASE_F(0, 2); PH_BAR_F;
  PH_FENCE_F; CVTWRITE_F(xvB, 1); COMPUTE_PHASE_F(0, 3);
  __syncthreads();
  COMPUTE_PHASE_F(1, 0); COMPUTE_PHASE_F(1, 1); COMPUTE_PHASE_F(1, 2); COMPUTE_PHASE_F(1, 3);

#undef STEP_F
#undef COMPUTE_PHASE_F
#undef CVTWRITE_F
#undef LOADB_F
#undef GLLA_F
#undef PH_BAR_F
#undef PH_FENCE_F

  float psum[2] = {0.f, 0.f};
#pragma unroll
  for (int fm = 0; fm < 4; ++fm)
#pragma unroll
    for (int fn = 0; fn < 2; ++fn)
#pragma unroll
      for (int r = 0; r < 16; ++r) {
        int row = wr * 128 + fm * 32 + (r & 3) + 8 * (r >> 2) + 4 * (lane >> 5);
        float x  = acc[fm][fn][r];
        float th = 1.0f - 2.0f / (__expf(2.0f * x) + 1.0f);
        psum[fn] += vbuf[row] * th;
      }
#pragma unroll
  for (int fn = 0; fn < 2; ++fn) psum[fn] += __shfl_xor(psum[fn], 32);
  if (lane < 32) {
    red[wr][wc * 64 + lane]      = psum[0];
    red[wr][wc * 64 + 32 + lane] = psum[1];
  }
  __syncthreads();
  if (tid < BN) {
    float val = red[0][tid] + red[1][tid];
    partials[(size_t)(dblk * B_ + b) * S_ + s0 + tid] = val;
  }
}

// ---------------------------------------------------------------------------
// softmax over S per batch; sums the 4 d-block partials first. Deterministic.
// ---------------------------------------------------------------------------
__global__ void softmax_kernel(const float* __restrict__ partials, float* __restrict__ out) {
  __shared__ float logit[S_];
  __shared__ float wred[2][4];
  int b = blockIdx.x, tid = threadIdx.x;
  int lane = tid & 63, wid = tid >> 6;
  float lmax = -1e30f;
  for (int i = tid; i < S_; i += 256) {
    float acc = 0.f;
#pragma unroll
    for (int d = 0; d < 4; ++d) acc += partials[(size_t)(d * B_ + b) * S_ + i];
    logit[i] = acc;
    lmax = fmaxf(lmax, acc);
  }
#pragma unroll
  for (int o = 32; o; o >>= 1) lmax = fmaxf(lmax, __shfl_xor(lmax, o));
  if (lane == 0) wred[0][wid] = lmax;
  __syncthreads();
  float m = fmaxf(fmaxf(wred[0][0], wred[0][1]), fmaxf(wred[0][2], wred[0][3]));
  float lsum = 0.f;
  for (int i = tid; i < S_; i += 256) {
    float ex = __expf(logit[i] - m);
    logit[i] = ex;
    lsum += ex;
  }
#pragma unroll
  for (int o = 32; o; o >>= 1) lsum += __shfl_xor(lsum, o);
  if (lane == 0) wred[1][wid] = lsum;
  __syncthreads();
  float tot = wred[1][0] + wred[1][1] + wred[1][2] + wred[1][3];
  float inv = 1.0f / tot;
  for (int i = tid; i < S_; i += 256) out[(size_t)b * S_ + i] = logit[i] * inv;
}

extern "C" void kernel_launch(void* const* d_in, const int* in_sizes, int n_in,
                              void* d_out, int out_size, void* d_ws, size_t ws_size,
                              hipStream_t stream) {
  const float* q = (const float*)d_in[0];
  const float* k = (const float*)d_in[1];
  const float* v = (const float*)d_in[2];
  const float* W = (const float*)d_in[3];
  const float* U = (const float*)d_in[4];

  // ws: [wf 2MB][uf 2MB][partials 1MB][bfmt 256MB (optional)]
  _Float16* wf = (_Float16*)d_ws;
  _Float16* uf = wf + (size_t)D_ * D_;
  float* partials = (float*)(uf + (size_t)D_ * D_);
  _Float16* bfmt = (_Float16*)((char*)d_ws + 5242880);
  const size_t NEED = 5242880ull + 268435456ull;  // 262 MB

  prep_kernel<<<dim3(512, 2), 256, 0, stream>>>(W, U, wf, uf);
  if (ws_size >= NEED) {
    kqprep_kernel<<<dim3(65536), 256, 0, stream>>>(k, q, bfmt);
    gemm_kernel<<<dim3(1024), 512, 0, stream>>>(v, wf, uf, bfmt, partials);
  } else {
    gemm_fb_kernel<<<dim3(1024), 512, 0, stream>>>(k, q, v, wf, uf, partials);
  }
  softmax_kernel<<<dim3(B_), 256, 0, stream>>>(partials, (float*)d_out);
}

// Round 13
// 418.008 us; speedup vs baseline: 1.1051x; 1.1051x over previous
//
#include <hip/hip_runtime.h>

#define D_ 1024
#define S_ 2048
#define B_ 32
#define BM 256
#define BN 256
#define BK 64
#define NKT 32   // K tiles: 16 from W/k + 16 from U/q (BK=64)
#define NPH 64   // half-K phases

typedef __attribute__((ext_vector_type(8))) _Float16 f16x8;  // 4 VGPR MFMA operand
typedef __attribute__((ext_vector_type(16))) float f32x16;   // MFMA 32x32 acc

// async global->LDS, 16B per lane; LDS dest = wave-uniform base + lane*16.
__device__ __forceinline__ void async_ld16(const void* g, void* l) {
  __builtin_amdgcn_global_load_lds(
      (const __attribute__((address_space(1))) void*)g,
      (__attribute__((address_space(3))) void*)l, 16, 0, 0);
}

// ---------------------------------------------------------------------------
// prep: W,U -> f16, FRAGMENT ORDER per 256x64 A-tile (2048 granules of 8):
//   granule = ((ks*8 + wr*4 + fm) << 6) | lane   (verified R9-R12)
// ---------------------------------------------------------------------------
__global__ void prep_kernel(const float* __restrict__ W, const float* __restrict__ U,
                            _Float16* __restrict__ wf, _Float16* __restrict__ uf) {
  int t = blockIdx.x * blockDim.x + threadIdx.x;  // [0, 131072) granules
  const float* src = blockIdx.y ? U : W;
  _Float16* dst = blockIdx.y ? uf : wf;

  int tile = t >> 11;        // [0,64) = dblk*16 + ktt
  int g    = t & 2047;
  int top  = g >> 6;         // [0,32) = ks*8 + wr*4 + fm
  int ks = top >> 3, wr = (top >> 2) & 1, fm = top & 3;
  int lane = g & 63, l31 = lane & 31, lhi = lane >> 5;
  int row   = wr * 128 + fm * 32 + l31;
  int chunk = ks * 2 + lhi;
  int d = (tile >> 4) * 256 + row;
  int e = (tile & 15) * 64 + chunk * 8;

  const float* p = src + (size_t)d * D_ + e;
  f16x8 hv;
#pragma unroll
  for (int j = 0; j < 8; ++j) hv[j] = (_Float16)p[j];  // RN
  *(f16x8*)(dst + (size_t)t * 8) = hv;                 // linear, coalesced
}

// ---------------------------------------------------------------------------
// kqprep: k,q (f32 [b,e,s]) -> f16 fragment-order B-tiles in ws (R11 verified).
// ---------------------------------------------------------------------------
__global__ void kqprep_kernel(const float* __restrict__ kten, const float* __restrict__ qten,
                              _Float16* __restrict__ bfmt) {
  size_t t = (size_t)blockIdx.x * 256 + threadIdx.x;  // [0, 16777216)
  int g    = (int)(t & 2047);
  int tile = (int)(t >> 11);
  int st   = tile & 7;
  int ktt  = (tile >> 3) & 15;
  int half = (tile >> 7) & 1;
  int b    = tile >> 8;
  int l31 = g & 31, clh = (g >> 5) & 1, w2 = (g >> 6) & 7, cks = g >> 9;
  int n = w2 * 32 + l31;
  int c = cks * 2 + clh;
  int e = ktt * 64 + c * 8;
  int s = st * 256 + n;

  const float* src = (half ? qten : kten) + (size_t)b * (D_ * S_) + (size_t)e * S_ + s;
  f16x8 hv;
#pragma unroll
  for (int j = 0; j < 8; ++j) hv[j] = (_Float16)src[(size_t)j * S_];  // RN
  *(f16x8*)(bfmt + t * 8) = hv;
}

// ---------------------------------------------------------------------------
// gemm v13: R11 geometry, DEEP pipeline (m201 depth). 64 half-K phases,
// 4 independent 16KB half-buffers per operand. Phase h:
//   12 ds_read buf[h&3] | 4 gll half(h+3)->buf[(h+3)&3] | s_barrier |
//   setprio(1) 16 MFMA setprio(0) | vmcnt(8) | s_barrier | sched_barrier(0)
// Ledger (4 instr/half): steady 12 in flight {h+1,h+2,h+3}; vmcnt(8) retires
// h+1 only -> 3 halves of latency cover, never drains to 0 mid-loop.
// Tail: phase 61 vmcnt(4), 62 vmcnt(0), 63 none.
// ---------------------------------------------------------------------------
__global__ void __launch_bounds__(512, 2)
gemm_kernel(const float* __restrict__ v,
            const _Float16* __restrict__ wf, const _Float16* __restrict__ uf,
            const _Float16* __restrict__ bfmt,
            float* __restrict__ partials) {
  __shared__ __align__(16) _Float16 Af[4][BM * 32];  // 4 x 16 KB (half-K subtiles)
  __shared__ __align__(16) _Float16 Bf[4][BN * 32];  // 4 x 16 KB
  __shared__ float vbuf[BM];
  __shared__ float red[2][BN];

  const int tid  = threadIdx.x;
  const int lane = tid & 63;
  const int wid  = tid >> 6;
  const int wr   = wid >> 2;        // [0,2) d-half (128 rows)
  const int wc   = wid & 3;         // [0,4) s-quarter (64 cols)

  int bid  = blockIdx.x;
  int g    = ((bid >> 5) << 3) | (bid & 7);  // [0,256): 4 dblk siblings same XCD
  int dblk = (bid >> 3) & 3;
  int st   = g & 7;
  int b    = g >> 3;
  int s0   = st * BN;

  if (tid < BM) vbuf[tid] = v[(size_t)b * D_ + dblk * BM + tid];
  __syncthreads();  // CRITICAL: drains the divergent v-load so every wave's
                    // vmcnt ledger is 0 before the counted pipeline starts.

  f32x16 acc[4][2];
#pragma unroll
  for (int i = 0; i < 4; ++i)
#pragma unroll
    for (int j = 0; j < 2; ++j)
#pragma unroll
      for (int r = 0; r < 16; ++r) acc[i][j][r] = 0.0f;

#define PH_FENCE asm volatile("" ::: "memory")
#define WAIT8 asm volatile("s_waitcnt vmcnt(8)" ::: "memory")
#define WAIT4 asm volatile("s_waitcnt vmcnt(4)" ::: "memory")
#define WAIT0 asm volatile("s_waitcnt vmcnt(0)" ::: "memory")

// Issue one half-K subtile (A: 16KB, B: 16KB) = 4 vmem instr/wave, fixed order.
#define GLLH(h_) do {                                                          \
    const int kt_ = (h_) >> 1, hh_ = (h_) & 1, bi_ = (h_) & 3;                 \
    const int half_ = kt_ >> 4, ktt_ = kt_ & 15;                               \
    const _Float16* at_ = (half_ ? uf : wf)                                    \
        + (size_t)(dblk * 16 + ktt_) * 16384 + (size_t)hh_ * 8192;             \
    const _Float16* bt_ = bfmt                                                 \
        + ((size_t)(((b * 2 + half_) * 16 + ktt_) * 8 + st)) * 16384           \
        + (size_t)hh_ * 8192;                                                  \
    async_ld16(at_ + (size_t)tid * 8,         &Af[bi_][(size_t)tid * 8]);      \
    async_ld16(at_ + (size_t)(tid + 512) * 8, &Af[bi_][(size_t)(tid + 512) * 8]); \
    async_ld16(bt_ + (size_t)tid * 8,         &Bf[bi_][(size_t)tid * 8]);      \
    async_ld16(bt_ + (size_t)(tid + 512) * 8, &Bf[bi_][(size_t)(tid + 512) * 8]); \
  } while (0)

// One phase: 12 ds_read | issue | barrier | 16 MFMA (prio) | wait | barrier | SB
#define PHASE(h_, ISSUE, WAITC) do {                                           \
    PH_FENCE;                                                                  \
    const int bi_ = (h_) & 3;                                                  \
    f16x8 a0_[4], a1_[4], b0_[2], b1_[2];                                      \
    _Pragma("unroll")                                                          \
    for (int fm = 0; fm < 4; ++fm)                                             \
      a0_[fm] = *(const f16x8*)&Af[bi_][(size_t)(((wr * 4 + fm) * 64 + lane)) * 8]; \
    _Pragma("unroll")                                                          \
    for (int fn = 0; fn < 2; ++fn)                                             \
      b0_[fn] = *(const f16x8*)&Bf[bi_][(size_t)(((wc * 2 + fn) * 64 + lane)) * 8]; \
    _Pragma("unroll")                                                          \
    for (int fm = 0; fm < 4; ++fm)                                             \
      a1_[fm] = *(const f16x8*)&Af[bi_][(size_t)(((8 + wr * 4 + fm) * 64 + lane)) * 8]; \
    _Pragma("unroll")                                                          \
    for (int fn = 0; fn < 2; ++fn)                                             \
      b1_[fn] = *(const f16x8*)&Bf[bi_][(size_t)(((8 + wc * 2 + fn) * 64 + lane)) * 8]; \
    ISSUE;                                                                     \
    __builtin_amdgcn_s_barrier();                                              \
    __builtin_amdgcn_s_setprio(1);                                             \
    _Pragma("unroll")                                                          \
    for (int fm = 0; fm < 4; ++fm)                                             \
      _Pragma("unroll")                                                        \
      for (int fn = 0; fn < 2; ++fn)                                           \
        acc[fm][fn] = __builtin_amdgcn_mfma_f32_32x32x16_f16(a0_[fm], b0_[fn], acc[fm][fn], 0, 0, 0); \
    _Pragma("unroll")                                                          \
    for (int fm = 0; fm < 4; ++fm)                                             \
      _Pragma("unroll")                                                        \
      for (int fn = 0; fn < 2; ++fn)                                           \
        acc[fm][fn] = __builtin_amdgcn_mfma_f32_32x32x16_f16(a1_[fm], b1_[fn], acc[fm][fn], 0, 0, 0); \
    __builtin_amdgcn_s_setprio(0);                                             \
    WAITC;                                                                     \
    __builtin_amdgcn_s_barrier();                                              \
    __builtin_amdgcn_sched_barrier(0);                                         \
  } while (0)

  // --- prologue: issue halves 0,1,2 (12 vmem); retire half 0; publish -------
  PH_FENCE;
  GLLH(0); GLLH(1); GLLH(2);
  WAIT8;
  __builtin_amdgcn_s_barrier();
  __builtin_amdgcn_sched_barrier(0);

  // --- main: phases 0..60 issue h+3 (3..63); steady vmcnt(8) ----------------
  for (int h = 0; h < NPH - 3; ++h) {
    PHASE(h, GLLH(h + 3), WAIT8);
  }
  // --- tail: ledger drains 8 -> 4 -> 0 --------------------------------------
  PHASE(61, , WAIT4);
  PHASE(62, , WAIT0);
  PHASE(63, , );

#undef PHASE
#undef GLLH
#undef WAIT0
#undef WAIT4
#undef WAIT8
#undef PH_FENCE

  // ---- epilogue: tanh, weight by v[d], column-reduce the 256 d-rows ----
  float psum[2] = {0.f, 0.f};
#pragma unroll
  for (int fm = 0; fm < 4; ++fm)
#pragma unroll
    for (int fn = 0; fn < 2; ++fn)
#pragma unroll
      for (int r = 0; r < 16; ++r) {
        // C/D layout: col = lane&31, row = (r&3)+8*(r>>2)+4*(lane>>5)
        int row = wr * 128 + fm * 32 + (r & 3) + 8 * (r >> 2) + 4 * (lane >> 5);
        float x  = acc[fm][fn][r];
        float th = 1.0f - 2.0f / (__expf(2.0f * x) + 1.0f);  // tanh(x)
        psum[fn] += vbuf[row] * th;
      }
#pragma unroll
  for (int fn = 0; fn < 2; ++fn) psum[fn] += __shfl_xor(psum[fn], 32);
  if (lane < 32) {
    red[wr][wc * 64 + lane]      = psum[0];
    red[wr][wc * 64 + 32 + lane] = psum[1];
  }
  __syncthreads();
  if (tid < BN) {
    float val = red[0][tid] + red[1][tid];
    partials[(size_t)(dblk * B_ + b) * S_ + s0 + tid] = val;
  }
}

// ---------------------------------------------------------------------------
// gemm fallback = R10 verbatim (reg-staged B, counted vmcnt(32)); used when
// ws_size can't hold the 256MB prepped-B buffer.
// ---------------------------------------------------------------------------
__global__ void __launch_bounds__(512, 2)
gemm_fb_kernel(const float* __restrict__ kten, const float* __restrict__ qten,
               const float* __restrict__ v,
               const _Float16* __restrict__ wf, const _Float16* __restrict__ uf,
               float* __restrict__ partials) {
  __shared__ __align__(16) _Float16 Af[2][BM * BK];
  __shared__ __align__(16) _Float16 Bf[2][BN * BK];
  __shared__ float vbuf[BM];
  __shared__ float red[2][BN];

  const int tid  = threadIdx.x;
  const int lane = tid & 63;
  const int wid  = tid >> 6;
  const int wr   = wid >> 2;
  const int wc   = wid & 3;

  int bid  = blockIdx.x;
  int g    = ((bid >> 5) << 3) | (bid & 7);
  int dblk = (bid >> 3) & 3;
  int st   = g & 7;
  int b    = g >> 3;
  int s0   = st * BN;

  if (tid < BM) vbuf[tid] = v[(size_t)b * D_ + dblk * BM + tid];

  f32x16 acc[4][2];
#pragma unroll
  for (int i = 0; i < 4; ++i)
#pragma unroll
    for (int j = 0; j < 2; ++j)
#pragma unroll
      for (int r = 0; r < 16; ++r) acc[i][j][r] = 0.0f;

  const int nB = tid & 255;
  const int kq = tid >> 8;

#define PH_FENCE_F asm volatile("" ::: "memory")
#define PH_BAR_F __builtin_amdgcn_s_barrier()

#define GLLA_F(ktn, buf, part) do {                                            \
    const int half_ = (ktn) >> 4, ktt_ = (ktn) & 15;                           \
    const _Float16* at_ = (half_ ? uf : wf) + (size_t)(dblk * 16 + ktt_) * 16384; \
    async_ld16(at_ + (size_t)(tid + (part) * 1024) * 8,                        \
               &Af[buf][(size_t)(tid + (part) * 1024) * 8]);                   \
    async_ld16(at_ + (size_t)(tid + (part) * 1024 + 512) * 8,                  \
               &Af[buf][(size_t)(tid + (part) * 1024 + 512) * 8]);             \
  } while (0)

#define LOADB_F(ktn, xv, h) do {                                               \
    const int half_ = (ktn) >> 4, ktt_ = (ktn) & 15;                           \
    const float* col_ = (half_ ? qten : kten) + (size_t)b * (D_ * S_)          \
                        + (size_t)(ktt_ * 64) * S_ + s0 + nB                   \
                        + (size_t)(kq * 32) * S_;                              \
    _Pragma("unroll")                                                          \
    for (int j = 16 * (h); j < 16 * (h) + 16; ++j) xv[j] = col_[(size_t)j * S_]; \
  } while (0)

#define CVTWRITE_F(xv, buf) do {                                               \
    _Pragma("unroll")                                                          \
    for (int cl = 0; cl < 4; ++cl) {                                           \
      f16x8 hv_;                                                               \
      _Pragma("unroll")                                                        \
      for (int w = 0; w < 8; ++w) hv_[w] = (_Float16)xv[cl * 8 + w];           \
      int c_ = kq * 4 + cl, cks_ = c_ >> 1, clh_ = c_ & 1;                     \
      int gnl_ = ((cks_ * 8 + (nB >> 6) * 2 + ((nB >> 5) & 1)) << 6)           \
                 | (clh_ << 5) | (nB & 31);                                    \
      *(f16x8*)&Bf[buf][(size_t)gnl_ * 8] = hv_;                               \
    }                                                                          \
  } while (0)

#define COMPUTE_PHASE_F(cur_, ks_) do {                                        \
    f16x8 af_[4], bf_[2];                                                      \
    _Pragma("unroll")                                                          \
    for (int fm = 0; fm < 4; ++fm)                                             \
      af_[fm] = *(const f16x8*)&Af[cur_][(size_t)(((ks_) * 8 + wr * 4 + fm) * 64 + lane) * 8]; \
    _Pragma("unroll")                                                          \
    for (int fn = 0; fn < 2; ++fn)                                             \
      bf_[fn] = *(const f16x8*)&Bf[cur_][(size_t)(((ks_) * 8 + wc * 2 + fn) * 64 + lane) * 8]; \
    __builtin_amdgcn_s_setprio(1);                                             \
    _Pragma("unroll")                                                          \
    for (int fm = 0; fm < 4; ++fm)                                             \
      _Pragma("unroll")                                                        \
      for (int fn = 0; fn < 2; ++fn)                                           \
        acc[fm][fn] = __builtin_amdgcn_mfma_f32_32x32x16_f16(af_[fm], bf_[fn], acc[fm][fn], 0, 0, 0); \
    __builtin_amdgcn_s_setprio(0);                                             \
  } while (0)

#define STEP_F(kt_, cur_, xvC_, xvN_) do {                                     \
    const int nxt_ = (cur_) ^ 1;                                               \
    PH_FENCE_F; GLLA_F((kt_) + 1, nxt_, 0); COMPUTE_PHASE_F(cur_, 0); PH_BAR_F;\
    PH_FENCE_F; GLLA_F((kt_) + 1, nxt_, 1); COMPUTE_PHASE_F(cur_, 1); PH_BAR_F;\
    PH_FENCE_F; LOADB_F((kt_) + 2, xvN_, 0); COMPUTE_PHASE_F(cur_, 2); PH_BAR_F;\
    PH_FENCE_F; LOADB_F((kt_) + 2, xvN_, 1); CVTWRITE_F(xvC_, nxt_);           \
              COMPUTE_PHASE_F(cur_, 3);                                        \
    asm volatile("s_waitcnt vmcnt(32) lgkmcnt(0)" ::: "memory");               \
    PH_BAR_F;                                                                  \
    __builtin_amdgcn_sched_barrier(0);                                         \
  } while (0)

  float xvA[32], xvB[32];
  LOADB_F(0, xvA, 0); LOADB_F(0, xvA, 1);
  GLLA_F(0, 0, 0);    GLLA_F(0, 0, 1);
  LOADB_F(1, xvB, 0); LOADB_F(1, xvB, 1);
  CVTWRITE_F(xvA, 0);
  __syncthreads();

  for (int it = 0; it < 15; ++it) {
    STEP_F(2 * it,     0, xvB, xvA);
    STEP_F(2 * it + 1, 1, xvA, xvB);
  }

  PH_FENCE_F; GLLA_F(31, 1, 0); COMPUTE_PHASE_F(0, 0); PH_BAR_F;
  PH_FENCE_F; GLLA_F(31, 1, 1); COMPUTE_PHASE_F(0, 1); PH_BAR_F;
  PH_FENCE_F; COMPUTE_PHASE_F(0, 2); PH_BAR_F;
  PH_FENCE_F; CVTWRITE_F(xvB, 1); COMPUTE_PHASE_F(0, 3);
  __syncthreads();
  COMPUTE_PHASE_F(1, 0); COMPUTE_PHASE_F(1, 1); COMPUTE_PHASE_F(1, 2); COMPUTE_PHASE_F(1, 3);

#undef STEP_F
#undef COMPUTE_PHASE_F
#undef CVTWRITE_F
#undef LOADB_F
#undef GLLA_F
#undef PH_BAR_F
#undef PH_FENCE_F

  float psum[2] = {0.f, 0.f};
#pragma unroll
  for (int fm = 0; fm < 4; ++fm)
#pragma unroll
    for (int fn = 0; fn < 2; ++fn)
#pragma unroll
      for (int r = 0; r < 16; ++r) {
        int row = wr * 128 + fm * 32 + (r & 3) + 8 * (r >> 2) + 4 * (lane >> 5);
        float x  = acc[fm][fn][r];
        float th = 1.0f - 2.0f / (__expf(2.0f * x) + 1.0f);
        psum[fn] += vbuf[row] * th;
      }
#pragma unroll
  for (int fn = 0; fn < 2; ++fn) psum[fn] += __shfl_xor(psum[fn], 32);
  if (lane < 32) {
    red[wr][wc * 64 + lane]      = psum[0];
    red[wr][wc * 64 + 32 + lane] = psum[1];
  }
  __syncthreads();
  if (tid < BN) {
    float val = red[0][tid] + red[1][tid];
    partials[(size_t)(dblk * B_ + b) * S_ + s0 + tid] = val;
  }
}

// ---------------------------------------------------------------------------
// softmax over S per batch; sums the 4 d-block partials first. Deterministic.
// ---------------------------------------------------------------------------
__global__ void softmax_kernel(const float* __restrict__ partials, float* __restrict__ out) {
  __shared__ float logit[S_];
  __shared__ float wred[2][4];
  int b = blockIdx.x, tid = threadIdx.x;
  int lane = tid & 63, wid = tid >> 6;
  float lmax = -1e30f;
  for (int i = tid; i < S_; i += 256) {
    float acc = 0.f;
#pragma unroll
    for (int d = 0; d < 4; ++d) acc += partials[(size_t)(d * B_ + b) * S_ + i];
    logit[i] = acc;
    lmax = fmaxf(lmax, acc);
  }
#pragma unroll
  for (int o = 32; o; o >>= 1) lmax = fmaxf(lmax, __shfl_xor(lmax, o));
  if (lane == 0) wred[0][wid] = lmax;
  __syncthreads();
  float m = fmaxf(fmaxf(wred[0][0], wred[0][1]), fmaxf(wred[0][2], wred[0][3]));
  float lsum = 0.f;
  for (int i = tid; i < S_; i += 256) {
    float ex = __expf(logit[i] - m);
    logit[i] = ex;
    lsum += ex;
  }
#pragma unroll
  for (int o = 32; o; o >>= 1) lsum += __shfl_xor(lsum, o);
  if (lane == 0) wred[1][wid] = lsum;
  __syncthreads();
  float tot = wred[1][0] + wred[1][1] + wred[1][2] + wred[1][3];
  float inv = 1.0f / tot;
  for (int i = tid; i < S_; i += 256) out[(size_t)b * S_ + i] = logit[i] * inv;
}

extern "C" void kernel_launch(void* const* d_in, const int* in_sizes, int n_in,
                              void* d_out, int out_size, void* d_ws, size_t ws_size,
                              hipStream_t stream) {
  const float* q = (const float*)d_in[0];
  const float* k = (const float*)d_in[1];
  const float* v = (const float*)d_in[2];
  const float* W = (const float*)d_in[3];
  const float* U = (const float*)d_in[4];

  // ws: [wf 2MB][uf 2MB][partials 1MB][bfmt 256MB (optional)]
  _Float16* wf = (_Float16*)d_ws;
  _Float16* uf = wf + (size_t)D_ * D_;
  float* partials = (float*)(uf + (size_t)D_ * D_);
  _Float16* bfmt = (_Float16*)((char*)d_ws + 5242880);
  const size_t NEED = 5242880ull + 268435456ull;  // 262 MB

  prep_kernel<<<dim3(512, 2), 256, 0, stream>>>(W, U, wf, uf);
  if (ws_size >= NEED) {
    kqprep_kernel<<<dim3(65536), 256, 0, stream>>>(k, q, bfmt);
    gemm_kernel<<<dim3(1024), 512, 0, stream>>>(v, wf, uf, bfmt, partials);
  } else {
    gemm_fb_kernel<<<dim3(2048 / 2), 512, 0, stream>>>(k, q, v, wf, uf, partials);
  }
  softmax_kernel<<<dim3(B_), 256, 0, stream>>>(partials, (float*)d_out);
}